// Round 9
// baseline (44.056 us; speedup 1.0000x reference)
//
#include <hip/hip_runtime.h>
#include <hip/hip_bf16.h>

// PhraseCompressor: B=4, T=4096, D=2048, P=1024, Lmax=8, c=128
#define DIM   2048
#define NC    256
#define CDIM  128
#define HALFCZ (16384u * 256u)   // elems per split-K partial

typedef __attribute__((ext_vector_type(8))) short short8;
typedef __attribute__((ext_vector_type(4))) float f32x4;

static __device__ __forceinline__ unsigned short f2bf(float f) {
    union { float f; unsigned u; } v; v.f = f;
    return (unsigned short)((v.u + 0x7fffu + ((v.u >> 16) & 1u)) >> 16);  // RNE
}

// pack 8 f32 -> 8 bf16 (compiler emits v_cvt_pk_bf16_f32 pairs)
static __device__ __forceinline__ short8 cvt8(float4 a, float4 b) {
    union { __hip_bfloat162 h2[4]; short8 s; } u;
    u.h2[0] = __float22bfloat162_rn(float2{a.x, a.y});
    u.h2[1] = __float22bfloat162_rn(float2{a.z, a.w});
    u.h2[2] = __float22bfloat162_rn(float2{b.x, b.y});
    u.h2[3] = __float22bfloat162_rn(float2{b.z, b.w});
    return u.s;
}

// two adjacent bf16 -> float2 (lo = v<<16, hi = v & 0xffff0000)
static __device__ __forceinline__ float2 ld2bf(const unsigned short* p) {
    unsigned v = *(const unsigned*)p;
    union { unsigned u; float f; } lo, hi;
    lo.u = v << 16;
    hi.u = v & 0xffff0000u;
    return float2{lo.f, hi.f};
}

// lgkm-only barrier: keep global (vmcnt) prefetch loads in flight across it.
#define BARRIER() { asm volatile("s_waitcnt lgkmcnt(0)" ::: "memory"); \
                    __builtin_amdgcn_s_barrier(); }

// ---------- Kernel 1: pack W_kv|W_z into fragment-major bf16 Wp ----------
// frag f 0..15 (cols f*16..), k-subtile s 0..63 (k = s*32..)
// Wp[((f*64+s)*64+l)*8+e] = W[f*16+(l&15)][s*32+(l>>4)*8+e]
__global__ __launch_bounds__(256) void convert_w(const float* __restrict__ Wkv,
                                                 const float* __restrict__ Wz,
                                                 unsigned short* __restrict__ Wp) {
    int tid = blockIdx.x * 256 + threadIdx.x;      // 65536 threads
    int l = tid & 63;
    int s = (tid >> 6) & 63;
    int f = tid >> 12;
    int n = f * 16 + (l & 15);
    int k = s * 32 + ((l >> 4) << 3);
    const float* src = (n < CDIM) ? (Wkv + (size_t)n * DIM + k)
                                  : (Wz + (size_t)(n - CDIM) * DIM + k);
    float4 f0 = *(const float4*)src;
    float4 f1 = *(const float4*)(src + 4);
    *(short8*)(Wp + (size_t)tid * 8) = cvt8(f0, f1);
}

// ---------- Kernel 2: CZp[ks][16384][256] = h @ W^T (K-slice, bf16 out) ------
// BM=64, BN=256, split-K=2. 256 thr = 4 waves; wave w: 64 rows x cols w*64..+63
// -> acc[4][4]. Grid 512 -> 2 blocks/CU. A: 64x64 bf16 LDS dbuf, XOR swizzle,
// reg-staged depth-2. B: fragment-major Wp (L2), reg-prefetched depth-1.
// Barriers are lgkm-only so prefetches stay in flight (T4); setprio on MFMA (T5).
__global__ __launch_bounds__(256) void gemm_hw(
    const float* __restrict__ H,
    const unsigned short* __restrict__ Wp,
    unsigned short* __restrict__ CZp)
{
    __shared__ unsigned char As[2 * 64 * 128];

    const int tid    = threadIdx.x;
    const int lane   = tid & 63;
    const int wave   = tid >> 6;        // 0..3
    const int wn     = wave * 64;
    const int bid    = blockIdx.x;
    const int kslice = bid & 1;
    const int m0     = (bid >> 1) * 64;

    unsigned short* CZout = CZp + (size_t)kslice * HALFCZ;

    // A staging: thread -> 16 consecutive floats of one row
    const int srow  = tid >> 2;          // 0..63
    const int scolf = (tid & 3) * 16;    // 0/16/32/48
    const float* gA = H + (size_t)(m0 + srow) * DIM + kslice * 1024 + scolf;
    const int swz   = (srow & 7) << 4;
    const int soff0 = (srow * 128 + scolf * 2) ^ swz;
    const int soff1 = (srow * 128 + scolf * 2 + 16) ^ swz;

    // B fragment base: frag index = wave*4 + j ; addr = wpb + j*32768 + s*512
    const unsigned short* wpb = Wp + (size_t)(wave * 4) * 32768 + lane * 8;

    f32x4 acc[4][4] = {};
    float4 p0[4], p1[4];
    short8 b0[2][4], b1[2][4];

#define LOADA(P, KT) { \
    _Pragma("unroll") \
    for (int q = 0; q < 4; ++q) P[q] = *(const float4*)(gA + (KT) * 64 + q * 4); }

#define LOADB(B, KT) { \
    _Pragma("unroll") \
    for (int ks = 0; ks < 2; ++ks) \
        _Pragma("unroll") \
        for (int j = 0; j < 4; ++j) \
            B[ks][j] = *(const short8*)(wpb + (size_t)j * 32768 + ((kslice << 5) + (KT) * 2 + ks) * 512); }

#define WRITES(BUFB, P) { \
    short8 lo_ = cvt8(P[0], P[1]); \
    short8 hi_ = cvt8(P[2], P[3]); \
    *(short8*)(As + (BUFB) + soff0) = lo_; \
    *(short8*)(As + (BUFB) + soff1) = hi_; }

#define COMPUTE(BUFB, B) { \
    short8 a_[2][4]; \
    _Pragma("unroll") \
    for (int ks = 0; ks < 2; ++ks) \
        _Pragma("unroll") \
        for (int i = 0; i < 4; ++i) { \
            int row_ = i * 16 + (lane & 15); \
            int off_ = (row_ * 128 + ks * 64 + ((lane >> 4) << 4)) ^ ((row_ & 7) << 4); \
            a_[ks][i] = *(const short8*)(As + (BUFB) + off_); \
        } \
    __builtin_amdgcn_s_setprio(1); \
    _Pragma("unroll") \
    for (int ks = 0; ks < 2; ++ks) \
        _Pragma("unroll") \
        for (int i = 0; i < 4; ++i) \
            _Pragma("unroll") \
            for (int j = 0; j < 4; ++j) \
                acc[i][j] = __builtin_amdgcn_mfma_f32_16x16x32_bf16(a_[ks][i], B[ks][j], acc[i][j], 0, 0, 0); \
    __builtin_amdgcn_s_setprio(0); }

    // ---- prologue: stage step0, prefetch step1 ----
    LOADA(p0, 0);
    LOADB(b0, 0);
    WRITES(0, p0);
    LOADA(p1, 1);
    BARRIER();

    // ---- 16 K-steps (K=1024), unrolled x2, 1 lgkm-barrier per step ----
    // HBM loads (LOADA) issued first in each half-step: longest latency first.
    for (int it = 0; it < 16; it += 2) {
        if (it + 2 < 16) LOADA(p0, it + 2);
        LOADB(b1, it + 1);
        WRITES(8192, p1);                       // stage it+1 into buf1
        COMPUTE(0, b0);
        BARRIER();

        if (it + 3 < 16) LOADA(p1, it + 3);
        if (it + 2 < 16) { LOADB(b0, it + 2); WRITES(0, p0); }
        COMPUTE(8192, b1);
        BARRIER();
    }

    // ---- epilogue: C/D layout col=lane&15, row=(lane>>4)*4+r ; bf16 store ----
    #pragma unroll
    for (int i = 0; i < 4; ++i)
        #pragma unroll
        for (int j = 0; j < 4; ++j)
            #pragma unroll
            for (int r = 0; r < 4; ++r) {
                int row = m0 + i * 16 + (lane >> 4) * 4 + r;
                int col = wn + j * 16 + (lane & 15);
                CZout[(size_t)row * NC + col] = f2bf(acc[i][j][r]);
            }
#undef LOADA
#undef LOADB
#undef WRITES
#undef COMPUTE
}

// ---------- Kernel 3: sum split-K + gather + masked softmax + reduce ----------
// 64 threads per phrase, 2 channels per thread (u32 bf16-pair gathers).
// Block = 4 phrases (one wave each); grid 1024.
__global__ __launch_bounds__(256) void finalize(
    const unsigned short* __restrict__ CZp,
    const int*   __restrict__ mask,
    const int*   __restrict__ idx,
    const float* __restrict__ Bpos,
    float*       __restrict__ out)
{
    const unsigned short* CZ0 = CZp;
    const unsigned short* CZ1 = CZp + HALFCZ;

    int t  = threadIdx.x;
    int lp = t & 63;                       // channel-pair index 0..63
    int q  = blockIdx.x * 4 + (t >> 6);    // linear phrase 0..4095
    q = __builtin_amdgcn_readfirstlane(q); // wave-uniform -> scalar loads below
    int b  = q >> 10;
    int ce = lp * 2;                       // even channel

    int rows[8];
    unsigned mbits = 0;
    #pragma unroll
    for (int l = 0; l < 8; ++l) {
        int m   = mask[q * 8 + l];
        int tok = idx[q * 8 + l];
        rows[l] = b * 4096 + tok;
        if (m) mbits |= 1u << l;
    }

    float2 z[8], c[8];
    float2 mx = {-1e30f, -1e30f};
    #pragma unroll
    for (int l = 0; l < 8; ++l) {
        if (mbits & (1u << l)) {
            size_t base = (size_t)rows[l] * NC;
            float2 z0 = ld2bf(CZ0 + base + CDIM + ce);
            float2 z1 = ld2bf(CZ1 + base + CDIM + ce);
            float2 bp = *(const float2*)(Bpos + l * CDIM + ce);
            z[l] = float2{z0.x + z1.x + bp.x, z0.y + z1.y + bp.y};
            float2 c0 = ld2bf(CZ0 + base + ce);
            float2 c1 = ld2bf(CZ1 + base + ce);
            c[l] = float2{c0.x + c1.x, c0.y + c1.y};
            mx.x = fmaxf(mx.x, z[l].x);
            mx.y = fmaxf(mx.y, z[l].y);
        }
    }

    float2 num = {0.f, 0.f}, den = {0.f, 0.f};
    #pragma unroll
    for (int l = 0; l < 8; ++l) {
        if (mbits & (1u << l)) {
            float wx = __expf(z[l].x - mx.x);
            float wy = __expf(z[l].y - mx.y);
            den.x += wx;            den.y += wy;
            num.x += wx * c[l].x;   num.y += wy * c[l].y;
        }
    }
    float2 r = mbits ? float2{num.x / den.x, num.y / den.y} : float2{0.f, 0.f};
    *(float2*)(out + (size_t)q * CDIM + ce) = r;
}

extern "C" void kernel_launch(void* const* d_in, const int* in_sizes, int n_in,
                              void* d_out, int out_size, void* d_ws, size_t ws_size,
                              hipStream_t stream) {
    const float* h    = (const float*)d_in[0];
    const int*   mask = (const int*)d_in[1];
    const int*   idx  = (const int*)d_in[2];
    const float* Wkv  = (const float*)d_in[3];
    const float* Wz   = (const float*)d_in[4];
    const float* Bpos = (const float*)d_in[5];
    float* out = (float*)d_out;

    unsigned short* Wp  = (unsigned short*)d_ws;                    // 1 MB packed W
    unsigned short* CZp = (unsigned short*)((char*)d_ws + 2 * 1024 * 1024); // 2x8.4 MB bf16

    convert_w<<<256, 256, 0, stream>>>(Wkv, Wz, Wp);
    gemm_hw<<<512, 256, 0, stream>>>(h, Wp, CZp);
    finalize<<<1024, 256, 0, stream>>>(CZp, mask, idx, Bpos, out);
}

// Round 11
// 41.989 us; speedup vs baseline: 1.0492x; 1.0492x over previous
//
#include <hip/hip_runtime.h>
#include <hip/hip_bf16.h>

// PhraseCompressor: B=4, T=4096, D=2048, P=1024, Lmax=8, c=128
#define DIM   2048
#define NC    256
#define CDIM  128
#define HALFCZ (16384u * 256u)   // elems per split-K partial

typedef __attribute__((ext_vector_type(8))) short short8;
typedef __attribute__((ext_vector_type(4))) float f32x4;

static __device__ __forceinline__ unsigned short f2bf(float f) {
    union { float f; unsigned u; } v; v.f = f;
    return (unsigned short)((v.u + 0x7fffu + ((v.u >> 16) & 1u)) >> 16);  // RNE
}

// pack 8 f32 -> 8 bf16 (compiler emits v_cvt_pk_bf16_f32 pairs)
static __device__ __forceinline__ short8 cvt8(float4 a, float4 b) {
    union { __hip_bfloat162 h2[4]; short8 s; } u;
    u.h2[0] = __float22bfloat162_rn(float2{a.x, a.y});
    u.h2[1] = __float22bfloat162_rn(float2{a.z, a.w});
    u.h2[2] = __float22bfloat162_rn(float2{b.x, b.y});
    u.h2[3] = __float22bfloat162_rn(float2{b.z, b.w});
    return u.s;
}

// two adjacent bf16 -> float2 (lo = v<<16, hi = v & 0xffff0000)
static __device__ __forceinline__ float2 ld2bf(const unsigned short* p) {
    unsigned v = *(const unsigned*)p;
    union { unsigned u; float f; } lo, hi;
    lo.u = v << 16;
    hi.u = v & 0xffff0000u;
    return float2{lo.f, hi.f};
}

// lgkm-only barrier: keep global (vmcnt) prefetch loads in flight across it.
#define BARRIER() { asm volatile("s_waitcnt lgkmcnt(0)" ::: "memory"); \
                    __builtin_amdgcn_s_barrier(); }

// ---------- Kernel 1: pack W_kv|W_z into fragment-major bf16 Wp ----------
// frag f 0..15 (cols f*16..), k-subtile s 0..63 (k = s*32..)
// Wp[((f*64+s)*64+l)*8+e] = W[f*16+(l&15)][s*32+(l>>4)*8+e]
__global__ __launch_bounds__(256) void convert_w(const float* __restrict__ Wkv,
                                                 const float* __restrict__ Wz,
                                                 unsigned short* __restrict__ Wp) {
    int tid = blockIdx.x * 256 + threadIdx.x;      // 65536 threads
    int l = tid & 63;
    int s = (tid >> 6) & 63;
    int f = tid >> 12;
    int n = f * 16 + (l & 15);
    int k = s * 32 + ((l >> 4) << 3);
    const float* src = (n < CDIM) ? (Wkv + (size_t)n * DIM + k)
                                  : (Wz + (size_t)(n - CDIM) * DIM + k);
    float4 f0 = *(const float4*)src;
    float4 f1 = *(const float4*)(src + 4);
    *(short8*)(Wp + (size_t)tid * 8) = cvt8(f0, f1);
}

// ---------- Kernel 2: CZp[ks][16384][256] = h @ W^T (K-slice, bf16 out) ------
// BM=64, BN=256, split-K=2. 512 thr = 8 waves; wave w: 64 rows x cols w*32..+31
// -> acc[4][2]. Grid 512 -> 2 blocks/CU = 16 waves/CU = 4 waves/SIMD.
// A: 64x64 bf16 LDS dbuf (16 KB), XOR swizzle, reg-staged depth-2.
// B: fragment-major Wp (L2), unique frags per wave, reg-prefetched depth-1.
// lgkm-only barriers (T4); setprio around MFMA cluster (T5).
__global__ __launch_bounds__(512, 4) void gemm_hw(
    const float* __restrict__ H,
    const unsigned short* __restrict__ Wp,
    unsigned short* __restrict__ CZp)
{
    __shared__ unsigned char As[2 * 64 * 128];

    const int tid    = threadIdx.x;
    const int lane   = tid & 63;
    const int wave   = tid >> 6;        // 0..7
    const int wn     = wave * 32;
    const int bid    = blockIdx.x;
    const int kslice = bid & 1;
    const int m0     = (bid >> 1) * 64;

    unsigned short* CZout = CZp + (size_t)kslice * HALFCZ;

    // A staging: thread -> 8 consecutive floats of one row (one short8 write)
    const int srow = tid >> 3;           // 0..63
    const int scol = (tid & 7) * 8;      // 0..56
    const float* gA = H + (size_t)(m0 + srow) * DIM + kslice * 1024 + scol;
    const int soff = (srow * 128 + scol * 2) ^ ((srow & 7) << 4);

    // B fragment base: frag index = wave*2 + j ; addr = wpb + j*32768 + s*512
    const unsigned short* wpb = Wp + (size_t)(wave * 2) * 32768 + lane * 8;

    f32x4 acc[4][2] = {};
    float4 pa0, pb0, pa1, pb1;
    short8 b0[2][2], b1[2][2];

#define LOADA(pa, pb, KT) { \
    pa = *(const float4*)(gA + (KT) * 64); \
    pb = *(const float4*)(gA + (KT) * 64 + 4); }

#define LOADB(B, KT) { \
    _Pragma("unroll") \
    for (int ks = 0; ks < 2; ++ks) \
        _Pragma("unroll") \
        for (int j = 0; j < 2; ++j) \
            B[ks][j] = *(const short8*)(wpb + (size_t)j * 32768 + ((kslice << 5) + (KT) * 2 + ks) * 512); }

#define WRITES(BUFB, pa, pb) { \
    *(short8*)(As + (BUFB) + soff) = cvt8(pa, pb); }

#define COMPUTE(BUFB, B) { \
    short8 a_[2][4]; \
    _Pragma("unroll") \
    for (int ks = 0; ks < 2; ++ks) \
        _Pragma("unroll") \
        for (int i = 0; i < 4; ++i) { \
            int row_ = i * 16 + (lane & 15); \
            int off_ = (row_ * 128 + ks * 64 + ((lane >> 4) << 4)) ^ ((row_ & 7) << 4); \
            a_[ks][i] = *(const short8*)(As + (BUFB) + off_); \
        } \
    __builtin_amdgcn_s_setprio(1); \
    _Pragma("unroll") \
    for (int ks = 0; ks < 2; ++ks) \
        _Pragma("unroll") \
        for (int i = 0; i < 4; ++i) \
            _Pragma("unroll") \
            for (int j = 0; j < 2; ++j) \
                acc[i][j] = __builtin_amdgcn_mfma_f32_16x16x32_bf16(a_[ks][i], B[ks][j], acc[i][j], 0, 0, 0); \
    __builtin_amdgcn_s_setprio(0); }

    // ---- prologue: stage step0, prefetch step1 ----
    LOADA(pa0, pb0, 0);
    LOADB(b0, 0);
    WRITES(0, pa0, pb0);
    LOADA(pa1, pb1, 1);
    BARRIER();

    // ---- 16 K-steps (K=1024), unrolled x2, 1 lgkm-barrier per step ----
    // HBM loads (LOADA) issued first in each half-step: longest latency first.
    for (int it = 0; it < 16; it += 2) {
        if (it + 2 < 16) LOADA(pa0, pb0, it + 2);
        LOADB(b1, it + 1);
        WRITES(8192, pa1, pb1);                 // stage it+1 into buf1
        COMPUTE(0, b0);
        BARRIER();

        if (it + 3 < 16) LOADA(pa1, pb1, it + 3);
        if (it + 2 < 16) { LOADB(b0, it + 2); WRITES(0, pa0, pb0); }
        COMPUTE(8192, b1);
        BARRIER();
    }

    // ---- epilogue: C/D layout col=lane&15, row=(lane>>4)*4+r ; bf16 store ----
    #pragma unroll
    for (int i = 0; i < 4; ++i)
        #pragma unroll
        for (int j = 0; j < 2; ++j)
            #pragma unroll
            for (int r = 0; r < 4; ++r) {
                int row = m0 + i * 16 + (lane >> 4) * 4 + r;
                int col = wn + j * 16 + (lane & 15);
                CZout[(size_t)row * NC + col] = f2bf(acc[i][j][r]);
            }
#undef LOADA
#undef LOADB
#undef WRITES
#undef COMPUTE
}

// ---------- Kernel 3: sum split-K + gather + masked softmax + reduce ----------
// 64 threads per phrase, 2 channels per thread (u32 bf16-pair gathers).
__global__ __launch_bounds__(256) void finalize(
    const unsigned short* __restrict__ CZp,
    const int*   __restrict__ mask,
    const int*   __restrict__ idx,
    const float* __restrict__ Bpos,
    float*       __restrict__ out)
{
    const unsigned short* CZ0 = CZp;
    const unsigned short* CZ1 = CZp + HALFCZ;

    int t  = threadIdx.x;
    int lp = t & 63;                       // channel-pair index 0..63
    int q  = blockIdx.x * 4 + (t >> 6);    // linear phrase 0..4095
    q = __builtin_amdgcn_readfirstlane(q); // wave-uniform -> scalar loads below
    int b  = q >> 10;
    int ce = lp * 2;                       // even channel

    int rows[8];
    unsigned mbits = 0;
    #pragma unroll
    for (int l = 0; l < 8; ++l) {
        int m   = mask[q * 8 + l];
        int tok = idx[q * 8 + l];
        rows[l] = b * 4096 + tok;
        if (m) mbits |= 1u << l;
    }

    float2 z[8], c[8];
    float2 mx = {-1e30f, -1e30f};
    #pragma unroll
    for (int l = 0; l < 8; ++l) {
        if (mbits & (1u << l)) {
            size_t base = (size_t)rows[l] * NC;
            float2 z0 = ld2bf(CZ0 + base + CDIM + ce);
            float2 z1 = ld2bf(CZ1 + base + CDIM + ce);
            float2 bp = *(const float2*)(Bpos + l * CDIM + ce);
            z[l] = float2{z0.x + z1.x + bp.x, z0.y + z1.y + bp.y};
            float2 c0 = ld2bf(CZ0 + base + ce);
            float2 c1 = ld2bf(CZ1 + base + ce);
            c[l] = float2{c0.x + c1.x, c0.y + c1.y};
            mx.x = fmaxf(mx.x, z[l].x);
            mx.y = fmaxf(mx.y, z[l].y);
        }
    }

    float2 num = {0.f, 0.f}, den = {0.f, 0.f};
    #pragma unroll
    for (int l = 0; l < 8; ++l) {
        if (mbits & (1u << l)) {
            float wx = __expf(z[l].x - mx.x);
            float wy = __expf(z[l].y - mx.y);
            den.x += wx;            den.y += wy;
            num.x += wx * c[l].x;   num.y += wy * c[l].y;
        }
    }
    float2 r = mbits ? float2{num.x / den.x, num.y / den.y} : float2{0.f, 0.f};
    *(float2*)(out + (size_t)q * CDIM + ce) = r;
}

extern "C" void kernel_launch(void* const* d_in, const int* in_sizes, int n_in,
                              void* d_out, int out_size, void* d_ws, size_t ws_size,
                              hipStream_t stream) {
    const float* h    = (const float*)d_in[0];
    const int*   mask = (const int*)d_in[1];
    const int*   idx  = (const int*)d_in[2];
    const float* Wkv  = (const float*)d_in[3];
    const float* Wz   = (const float*)d_in[4];
    const float* Bpos = (const float*)d_in[5];
    float* out = (float*)d_out;

    unsigned short* Wp  = (unsigned short*)d_ws;                    // 1 MB packed W
    unsigned short* CZp = (unsigned short*)((char*)d_ws + 2 * 1024 * 1024); // 2x8.4 MB bf16

    convert_w<<<256, 256, 0, stream>>>(Wkv, Wz, Wp);
    gemm_hw<<<512, 512, 0, stream>>>(h, Wp, CZp);
    finalize<<<1024, 256, 0, stream>>>(CZp, mask, idx, Bpos, out);
}